// Round 1
// baseline (205.338 us; speedup 1.0000x reference)
//
#include <hip/hip_runtime.h>

#define MARGIN 0.1f

// One 32-lane group per row (G=128 -> 4 floats/lane via float4).
// Full wave (64 lanes) covers 2 consecutive rows = 1 KiB contiguous.
__global__ __launch_bounds__(256) void margin_loss_kernel(
    const float* __restrict__ inputs,
    const int*   __restrict__ labels,
    float*       __restrict__ out,
    int N, float inv_denom)
{
    const int G = 128;
    const int tid     = blockIdx.x * blockDim.x + threadIdx.x;
    const int group   = tid >> 5;      // row-group id (32 threads per row)
    const int lane32  = tid & 31;
    const int ngroups = (gridDim.x * blockDim.x) >> 5;

    float partial = 0.0f;

    for (int row = group; row < N; row += ngroups) {
        const int lbl = labels[row];   // uniform within the 32-lane group
        const float4 v = ((const float4*)(inputs + (size_t)row * G))[lane32];

        // Element (lbl & 3) of the owner lane's float4; lbl is group-uniform
        // so this select is non-divergent.
        float cand;
        switch (lbl & 3) {
            case 0:  cand = v.x; break;
            case 1:  cand = v.y; break;
            case 2:  cand = v.z; break;
            default: cand = v.w; break;
        }
        const float correct = __shfl(cand, lbl >> 2, 32);  // broadcast in 32-group

        float s = fmaxf(MARGIN - correct + v.x, 0.0f)
                + fmaxf(MARGIN - correct + v.y, 0.0f)
                + fmaxf(MARGIN - correct + v.z, 0.0f)
                + fmaxf(MARGIN - correct + v.w, 0.0f);

        // j == label contributes max(0, (M-c)+c) == MARGIN (to ~1 ulp);
        // subtract it once per row instead of masking.
        if (lane32 == 0) s -= MARGIN;

        partial += s;
    }

    // Wave-level reduction across all 64 lanes.
    #pragma unroll
    for (int off = 32; off > 0; off >>= 1)
        partial += __shfl_down(partial, off, 64);

    __shared__ float wsum[4];
    const int wave = threadIdx.x >> 6;
    if ((threadIdx.x & 63) == 0) wsum[wave] = partial;
    __syncthreads();

    if (threadIdx.x == 0) {
        const float bs = (wsum[0] + wsum[1]) + (wsum[2] + wsum[3]);
        atomicAdd(out, bs * inv_denom);   // device-scope by default on CDNA
    }
}

extern "C" void kernel_launch(void* const* d_in, const int* in_sizes, int n_in,
                              void* d_out, int out_size, void* d_ws, size_t ws_size,
                              hipStream_t stream) {
    const float* inputs = (const float*)d_in[0];
    const int*   labels = (const int*)d_in[1];
    float*       out    = (float*)d_out;

    const int N = in_sizes[1];         // 262144 rows
    const int G = 128;
    const float inv_denom = 1.0f / ((float)N * (float)(G - 1));

    // d_out is poisoned with 0xAA before every call — zero it (async, capturable).
    hipMemsetAsync(out, 0, sizeof(float), stream);

    const int block = 256;
    const int grid  = 2048;            // 8 workgroups/CU on 256 CUs; grid-stride inside
    margin_loss_kernel<<<grid, block, 0, stream>>>(inputs, labels, out, N, inv_denom);
}

// Round 2
// 191.885 us; speedup vs baseline: 1.0701x; 1.0701x over previous
//
#include <hip/hip_runtime.h>

#define MARGIN 0.1f
#define NBLOCKS 2048
#define BLOCK 256

// Kernel 1: hinge-sum partials per block.
// One 32-lane group per 16 consecutive rows (G=128 -> 4 floats/lane via float4).
// Unrolled 4 rows/iter: 4 independent float4 loads + one int4 label load in flight.
// Includes the j==label term (== MARGIN to ~1ulp); corrected in kernel 2.
__global__ __launch_bounds__(BLOCK) void margin_partials_kernel(
    const float* __restrict__ inputs,
    const int*   __restrict__ labels,
    float*       __restrict__ partials,
    int N)
{
    const int G = 128;
    const int ROWS_PER_GROUP = 16;
    const int tid     = blockIdx.x * blockDim.x + threadIdx.x;
    const int group   = tid >> 5;
    const int lane32  = tid & 31;
    const int ngroups = (gridDim.x * blockDim.x) >> 5;

    float partial = 0.0f;

    for (int base = group * ROWS_PER_GROUP; base < N;
         base += ngroups * ROWS_PER_GROUP) {
        #pragma unroll
        for (int c = 0; c < ROWS_PER_GROUP; c += 4) {
            const int r0 = base + c;
            // 4 labels in one 16B load (uniform across the group).
            const int4 lab = *(const int4*)(labels + r0);

            const float4 v0 = ((const float4*)(inputs + (size_t)(r0 + 0) * G))[lane32];
            const float4 v1 = ((const float4*)(inputs + (size_t)(r0 + 1) * G))[lane32];
            const float4 v2 = ((const float4*)(inputs + (size_t)(r0 + 2) * G))[lane32];
            const float4 v3 = ((const float4*)(inputs + (size_t)(r0 + 3) * G))[lane32];

            #pragma unroll
            for (int k = 0; k < 4; ++k) {
                const int lbl = (k == 0) ? lab.x : (k == 1) ? lab.y
                              : (k == 2) ? lab.z : lab.w;
                const float4 v = (k == 0) ? v0 : (k == 1) ? v1
                               : (k == 2) ? v2 : v3;
                float cand;
                switch (lbl & 3) {            // lbl is group-uniform: no divergence
                    case 0:  cand = v.x; break;
                    case 1:  cand = v.y; break;
                    case 2:  cand = v.z; break;
                    default: cand = v.w; break;
                }
                const float mc = MARGIN - __shfl(cand, lbl >> 2, 32);
                partial += fmaxf(mc + v.x, 0.0f) + fmaxf(mc + v.y, 0.0f)
                         + fmaxf(mc + v.z, 0.0f) + fmaxf(mc + v.w, 0.0f);
            }
        }
    }

    // Reduce across the full 64-lane wave.
    #pragma unroll
    for (int off = 32; off > 0; off >>= 1)
        partial += __shfl_down(partial, off, 64);

    __shared__ float wsum[BLOCK / 64];
    const int wave = threadIdx.x >> 6;
    if ((threadIdx.x & 63) == 0) wsum[wave] = partial;
    __syncthreads();

    if (threadIdx.x == 0) {
        float bs = 0.0f;
        #pragma unroll
        for (int w = 0; w < BLOCK / 64; ++w) bs += wsum[w];
        partials[blockIdx.x] = bs;   // plain store: overwrites 0xAA poison
    }
}

// Kernel 2: reduce NBLOCKS partials, subtract the j==label contribution
// (MARGIN per row), scale, store the scalar.
__global__ __launch_bounds__(BLOCK) void margin_finalize_kernel(
    const float* __restrict__ partials,
    float*       __restrict__ out,
    int N, float inv_denom)
{
    float s = 0.0f;
    for (int i = threadIdx.x; i < NBLOCKS; i += BLOCK)
        s += partials[i];

    #pragma unroll
    for (int off = 32; off > 0; off >>= 1)
        s += __shfl_down(s, off, 64);

    __shared__ float wsum[BLOCK / 64];
    const int wave = threadIdx.x >> 6;
    if ((threadIdx.x & 63) == 0) wsum[wave] = s;
    __syncthreads();

    if (threadIdx.x == 0) {
        float total = 0.0f;
        #pragma unroll
        for (int w = 0; w < BLOCK / 64; ++w) total += wsum[w];
        total -= MARGIN * (float)N;          // remove j==label terms
        *out = total * inv_denom;
    }
}

extern "C" void kernel_launch(void* const* d_in, const int* in_sizes, int n_in,
                              void* d_out, int out_size, void* d_ws, size_t ws_size,
                              hipStream_t stream) {
    const float* inputs = (const float*)d_in[0];
    const int*   labels = (const int*)d_in[1];
    float*       out    = (float*)d_out;
    float*       partials = (float*)d_ws;    // NBLOCKS floats of scratch

    const int N = in_sizes[1];               // 262144 rows
    const int G = 128;
    const float inv_denom = 1.0f / ((float)N * (float)(G - 1));

    margin_partials_kernel<<<NBLOCKS, BLOCK, 0, stream>>>(inputs, labels, partials, N);
    margin_finalize_kernel<<<1, BLOCK, 0, stream>>>(partials, out, N, inv_denom);
}